// Round 14
// baseline (188.663 us; speedup 1.0000x reference)
//
#include <hip/hip_runtime.h>
#include <stdint.h>

// BNN conv3d forward: x (8,32,16,160,160) f32, w (32,32,1,3,3) f32
// out = conv3d(x, we), we = (mean|w| over taps)*sign(w). kD=1 -> 2D conv.
// Implicit GEMM, mfma_f32_16x16x32_f16 (M=16 w-pos, N=16 out-ch, K=32 in-ch).
//
// Round-14: R13's global_load_lds DMA pipeline (the proven 188us structure)
// squeezed to 81920 B LDS -> 2 RESIDENT BLOCKS/CU. The co-resident block
// covers vmcnt/pack/barrier bubbles -> read pipe never idles.
//  - ring: 4 slots x 160 cells x 64 B = 40960 (halo columns dropped; w-edge
//    fragments handled by clamp+select at the 2 static edge sites, R7-proven)
//  - scratch: 2 slots x 20480 = 40960 (was 3; slot algebra %2 re-audited:
//    pack-read and DMA-write of a slot are always barrier-separated)
//  - schedule per iter t (same as R13, DMA one later):
//      VMCNT(12); PACK(t+2); barrier; DMA(t+4); COMPUTE(t)
//  - 512 blocks (8n*16d*4hc of 40 rows) = ALL resident, one generation.

typedef _Float16 half8  __attribute__((ext_vector_type(8)));
typedef float    floatx4 __attribute__((ext_vector_type(4)));

#define DHW 409600          // channel stride (floats)
#define HW  25600           // d stride
#define RING_SLOT_B 10240   // 160 cells * 64 B
#define RING_B      40960   // 4 ring slots
#define SCR_SLOT_B  20480   // 160 w * 32 ch * 4 B
#define LDS_TOTAL   81920   // ring + 2 scratch slots = exactly 2 blocks/CU

__device__ __forceinline__ int w1s(int w1) { return w1 ^ ((w1 >> 2) & 1); }
__device__ __forceinline__ int f2v(int w1) { return ((w1 >> 1) ^ (w1 >> 3)) & 3; }

typedef const __attribute__((address_space(1))) uint32_t* gas1;
typedef __attribute__((address_space(3))) uint32_t* las3;
__device__ __forceinline__ void gld16(const void* g, void* l) {
    __builtin_amdgcn_global_load_lds((gas1)g, (las3)l, 16, 0, 0);
}
#define VMCNT(N) do { asm volatile("s_waitcnt vmcnt(" #N ")" ::: "memory"); \
                      __builtin_amdgcn_sched_barrier(0); } while (0)
__device__ __forceinline__ void barrier_raw() {
    __builtin_amdgcn_sched_barrier(0);
    asm volatile("s_waitcnt lgkmcnt(0)" ::: "memory");
    __builtin_amdgcn_s_barrier();
    __builtin_amdgcn_sched_barrier(0);
}

// ---- kernel 1: effective-weight fragments -> ws (18 KB) -------------------
__global__ void bnn_wprep_kernel(const float* __restrict__ w,
                                 _Float16* __restrict__ ws) {
    const int tid = threadIdx.x;
    #pragma unroll
    for (int p4 = 0; p4 < 4; ++p4) {
        const int oi = tid * 4 + p4;
        const int o  = oi >> 5;
        const int i  = oi & 31;
        const float* wp = w + oi * 9;
        float s = 0.f;
        #pragma unroll
        for (int t = 0; t < 9; ++t) s += fabsf(wp[t]);
        s *= (1.f / 9.f);
        const int l = ((i >> 3) << 4) | (o & 15);
        const int p = o >> 4;
        const int j = i & 7;
        #pragma unroll
        for (int t = 0; t < 9; ++t) {
            const float v  = wp[t];
            const float sg = (v > 0.f) ? 1.f : ((v < 0.f) ? -1.f : 0.f);
            ws[((t * 2 + p) * 64 + l) * 8 + j] = (_Float16)(s * sg);
        }
    }
}

// ---- kernel 2: the conv ---------------------------------------------------
__global__ __launch_bounds__(320) void bnn_conv3d_dma(
        const float* __restrict__ x, const _Float16* __restrict__ ws,
        float* __restrict__ out) {
    extern __shared__ __align__(16) char lds[];

    const int tid  = threadIdx.x;
    const int lane = tid & 63;
    const int wv   = tid >> 6;         // 0..4

    const int bid = blockIdx.x;        // 512 = 8n * 16d * 4 h-chunks
    const int hc  = bid & 3;
    const int d   = (bid >> 2) & 15;
    const int n   = bid >> 6;
    const int h0  = hc * 40;           // out rows h0..h0+39; in rows h0-1..h0+40

    // ---- DMA source bases: instr q = ch-octet q, wave panel w=[32wv,32wv+32)
    // lane: ch = q*8 + (lane>>3), w = 32wv + (lane&7)*4 (float4)
    const float* qb[4];
    {
        const int chl = lane >> 3;
        const int wl  = (lane & 7) * 4;
        #pragma unroll
        for (int q = 0; q < 4; ++q)
            qb[q] = x + (size_t)(n * 32 + q * 8 + chl) * DHW + d * HW + wv * 32 + wl;
    }

    // ---- weight fragments first (so the vmcnt(0) drain precedes all DMA) --
    half8 wf0[9], wf1[9];
    {
        const half8* fb = (const half8*)ws;
        #pragma unroll
        for (int t = 0; t < 9; ++t) {
            wf0[t] = fb[(t * 2 + 0) * 64 + lane];
            wf1[t] = fb[(t * 2 + 1) * 64 + lane];
        }
    }
    asm volatile("s_waitcnt vmcnt(0)" ::: "memory");
    __builtin_amdgcn_sched_barrier(0);

    // ---- PACK precompute: lane pair handles ring cell pcell, 16 channels --
    const int pcell = 32 * wv + (lane >> 1);         // swizzled cell id 0..159
    const int w1p   = w1s(pcell);                    // logical w (involution)
    const int wloc  = w1p - wv * 32;                 // 0..31 within wave panel
    const int chb   = (lane & 1) * 16;
    int soff[16];                                    // scratch byte offsets
    #pragma unroll
    for (int c = 0; c < 16; ++c) {
        const int ch = chb + c;
        soff[c] = (wv * 4 + (ch >> 3)) * 1024 + ((ch & 7) * 8 + (wloc >> 2)) * 16
                + (wloc & 3) * 4;
    }
    const int f2p = f2v(pcell);
    const int rb0 = pcell * 64 + ((((lane & 1) * 2)     ^ f2p) * 16);
    const int rb1 = pcell * 64 + ((((lane & 1) * 2 + 1) ^ f2p) * 16);

    // ---- COMPUTE precompute (R5 fragment path; w-edges via clamp+select) --
    const int s16 = lane & 15, kgr = lane >> 4;
    int rdo[2][3];
    #pragma unroll
    for (int gi = 0; gi < 2; ++gi)
        #pragma unroll
        for (int kw = 0; kw < 3; ++kw) {
            int wq = (2 * wv + gi) * 16 + s16 + kw - 1;      // -1..160
            wq = wq < 0 ? 0 : (wq > 159 ? 159 : wq);
            rdo[gi][kw] = (w1s(wq) * 32 + ((kgr ^ f2v(wq)) * 8)) * 2;  // bytes
        }
    const bool okA = (wv * 32 + s16 - 1) >= 0;        // site (gi=0,kw=0)
    const bool okB = (wv * 32 + 16 + s16 + 1) < 160;  // site (gi=1,kw=2)
    float* ob = out + (size_t)(n * 32 + s16) * DHW + d * HW + wv * 32 + kgr * 4;

    auto DMA = [&](int r) {            // 4 instrs/wave; clamped h (garbage OK)
        int h = h0 - 1 + r; h = h < 0 ? 0 : (h > 159 ? 159 : h);
        char* dst = lds + RING_B + (r & 1) * SCR_SLOT_B + wv * 4096;
        #pragma unroll
        for (int q = 0; q < 4; ++q)
            gld16(qb[q] + h * 160, dst + q * 1024);
        __builtin_amdgcn_sched_barrier(0);   // pin issue
    };
    auto PACK = [&](int r) {           // scratch f32 -> f16 ring (own-wave)
        const int hr = h0 - 1 + r;
        const char* sl = lds + RING_B + (r & 1) * SCR_SLOT_B;
        char* rg = lds + (r & 3) * RING_SLOT_B;
        half8 o0 = {}, o1 = {};
        if (hr >= 0 && hr < 160) {     // block-uniform; OOB rows -> zeros
            float f[16];
            #pragma unroll
            for (int c = 0; c < 16; ++c) f[c] = *(const float*)(sl + soff[c]);
            #pragma unroll
            for (int c = 0; c < 8; ++c) { o0[c] = (_Float16)f[c]; o1[c] = (_Float16)f[c + 8]; }
        }
        *(half8*)(rg + rb0) = o0;
        *(half8*)(rg + rb1) = o1;
    };
    auto COMPUTE = [&](int t) {        // output row h0+t; ring rows t..t+2
        const half8 zh = {};
        #pragma unroll
        for (int gi = 0; gi < 2; ++gi) {
            floatx4 a0 = {0.f, 0.f, 0.f, 0.f};
            floatx4 a1 = {0.f, 0.f, 0.f, 0.f};
            #pragma unroll
            for (int kh = 0; kh < 3; ++kh) {
                const char* sb = lds + ((t + kh) & 3) * RING_SLOT_B;
                #pragma unroll
                for (int kw = 0; kw < 3; ++kw) {
                    half8 a = *(const half8*)(sb + rdo[gi][kw]);
                    if (gi == 0 && kw == 0) a = okA ? a : zh;   // w = -1 edge
                    if (gi == 1 && kw == 2) a = okB ? a : zh;   // w = 160 edge
                    const int tp = kh * 3 + kw;
                    a0 = __builtin_amdgcn_mfma_f32_16x16x32_f16(a, wf0[tp], a0, 0, 0, 0);
                    a1 = __builtin_amdgcn_mfma_f32_16x16x32_f16(a, wf1[tp], a1, 0, 0, 0);
                }
            }
            float* op = ob + (size_t)(h0 + t) * 160 + gi * 16;
            *(floatx4*)op = a0;                       // o 0..15
            *(floatx4*)(op + (size_t)16 * DHW) = a1;  // o 16..31
        }
    };

    // ---------------- pipeline (vmcnt audited per wave: 4 DMA + 4 stores) ---
    DMA(0); DMA(1);                    // slots 0,1
    VMCNT(4);  PACK(0);                // wait D0 (D1 younger)
    barrier_raw(); DMA(2);             // slot 0 (read drained by barrier)
    VMCNT(4);  PACK(1);                // wait D1 (D2 younger)
    barrier_raw(); DMA(3);             // slot 1
    // t=0: outstanding D2,D3 -> wait D2
    VMCNT(4);  PACK(2); barrier_raw(); DMA(4); COMPUTE(0);
    // t=1: outstanding D3,D4,S0 -> wait D3
    VMCNT(8);  PACK(3); barrier_raw(); DMA(5); COMPUTE(1);
    // steady t=2..37: outstanding S(t-2),D(t+3),S(t-1) younger than D(t+2)
    for (int t = 2; t <= 37; ++t) {
        VMCNT(12); PACK(t + 2); barrier_raw(); DMA(t + 4); COMPUTE(t);
    }
    // t=38: wait D40 (younger: S36,D41,S37)
    VMCNT(12); PACK(40); barrier_raw(); COMPUTE(38);
    // t=39: wait D41 (younger: S37,S38)
    VMCNT(8);  PACK(41); barrier_raw(); COMPUTE(39);
}

extern "C" void kernel_launch(void* const* d_in, const int* in_sizes, int n_in,
                              void* d_out, int out_size, void* d_ws, size_t ws_size,
                              hipStream_t stream) {
    const float* x = (const float*)d_in[0];
    const float* w = (const float*)d_in[1];
    float* out = (float*)d_out;
    _Float16* ws = (_Float16*)d_ws;     // 9216 halfs = 18 KB scratch
    bnn_wprep_kernel<<<dim3(1), dim3(256), 0, stream>>>(w, ws);
    (void)hipFuncSetAttribute((const void*)&bnn_conv3d_dma,
                              hipFuncAttributeMaxDynamicSharedMemorySize, LDS_TOTAL);
    // grid: 8 n * 16 d * 4 h-chunks of 40 rows -> 512 blocks, ALL resident
    bnn_conv3d_dma<<<dim3(512), dim3(320), LDS_TOTAL, stream>>>(x, ws, out);
}

// Round 15
// 186.894 us; speedup vs baseline: 1.0095x; 1.0095x over previous
//
#include <hip/hip_runtime.h>
#include <stdint.h>

// BNN conv3d forward: x (8,32,16,160,160) f32, w (32,32,1,3,3) f32
// out = conv3d(x, we), we = (mean|w| over taps)*sign(w). kD=1 -> 2D conv.
// Implicit GEMM, mfma_f32_16x16x32_f16 (M=16 w-pos, N=16 out-ch, K=32 in-ch).
//
// Round-15: R13's proven global_load_lds DMA pipeline, LDS cut to 61440 B
// STATIC (ring 4x10240 + ONE 20480 scratch slot) -> 2 blocks/CU guaranteed
// (dynamic-LDS +512 padding made R14's 81920 request miss the 2-block fit;
// static allocs report exact). Scratch is wave-private so depth-1 is
// race-free: PACK(t+2) reads are lgkm-drained by the barrier before the
// same wave's DMA(t+3) writes land. Steady iter:
//   VMCNT(4); PACK(t+2); barrier; DMA(t+3); COMPUTE(t)
// In-flight reads: 20KB/block x 2 blocks = 40KB/CU >= 22KB Little's-law
// need; the co-resident block covers vmcnt/pack/barrier bubbles.

typedef _Float16 half8  __attribute__((ext_vector_type(8)));
typedef float    floatx4 __attribute__((ext_vector_type(4)));

#define DHW 409600          // channel stride (floats)
#define HW  25600           // d stride
#define RING_SLOT_B 10240   // 160 cells * 64 B
#define RING_B      40960   // 4 ring slots
#define LDS_TOTAL   61440   // ring + 1 scratch slot (20480) -> 2 blocks/CU

__device__ __forceinline__ int w1s(int w1) { return w1 ^ ((w1 >> 2) & 1); }
__device__ __forceinline__ int f2v(int w1) { return ((w1 >> 1) ^ (w1 >> 3)) & 3; }

typedef const __attribute__((address_space(1))) uint32_t* gas1;
typedef __attribute__((address_space(3))) uint32_t* las3;
__device__ __forceinline__ void gld16(const void* g, void* l) {
    __builtin_amdgcn_global_load_lds((gas1)g, (las3)l, 16, 0, 0);
}
#define VMCNT(N) do { asm volatile("s_waitcnt vmcnt(" #N ")" ::: "memory"); \
                      __builtin_amdgcn_sched_barrier(0); } while (0)
__device__ __forceinline__ void barrier_raw() {
    __builtin_amdgcn_sched_barrier(0);
    asm volatile("s_waitcnt lgkmcnt(0)" ::: "memory");
    __builtin_amdgcn_s_barrier();
    __builtin_amdgcn_sched_barrier(0);
}

// ---- kernel 1: effective-weight fragments -> ws (18 KB) -------------------
__global__ void bnn_wprep_kernel(const float* __restrict__ w,
                                 _Float16* __restrict__ ws) {
    const int tid = threadIdx.x;
    #pragma unroll
    for (int p4 = 0; p4 < 4; ++p4) {
        const int oi = tid * 4 + p4;
        const int o  = oi >> 5;
        const int i  = oi & 31;
        const float* wp = w + oi * 9;
        float s = 0.f;
        #pragma unroll
        for (int t = 0; t < 9; ++t) s += fabsf(wp[t]);
        s *= (1.f / 9.f);
        const int l = ((i >> 3) << 4) | (o & 15);
        const int p = o >> 4;
        const int j = i & 7;
        #pragma unroll
        for (int t = 0; t < 9; ++t) {
            const float v  = wp[t];
            const float sg = (v > 0.f) ? 1.f : ((v < 0.f) ? -1.f : 0.f);
            ws[((t * 2 + p) * 64 + l) * 8 + j] = (_Float16)(s * sg);
        }
    }
}

// ---- kernel 2: the conv ---------------------------------------------------
__global__ __launch_bounds__(320, 3) void bnn_conv3d_dma(
        const float* __restrict__ x, const _Float16* __restrict__ ws,
        float* __restrict__ out) {
    __shared__ __align__(16) char lds[LDS_TOTAL];   // STATIC: exact size

    const int tid  = threadIdx.x;
    const int lane = tid & 63;
    const int wv   = tid >> 6;         // 0..4

    const int bid = blockIdx.x;        // 512 = 8n * 16d * 4 h-chunks
    const int hc  = bid & 3;
    const int d   = (bid >> 2) & 15;
    const int n   = bid >> 6;
    const int h0  = hc * 40;           // out rows h0..h0+39; in rows h0-1..h0+40

    // ---- DMA source bases: instr q = ch-octet q, wave panel w=[32wv,32wv+32)
    // lane: ch = q*8 + (lane>>3), w = 32wv + (lane&7)*4 (float4)
    const float* qb[4];
    {
        const int chl = lane >> 3;
        const int wl  = (lane & 7) * 4;
        #pragma unroll
        for (int q = 0; q < 4; ++q)
            qb[q] = x + (size_t)(n * 32 + q * 8 + chl) * DHW + d * HW + wv * 32 + wl;
    }

    // ---- weight fragments first (so the vmcnt(0) drain precedes all DMA) --
    half8 wf0[9], wf1[9];
    {
        const half8* fb = (const half8*)ws;
        #pragma unroll
        for (int t = 0; t < 9; ++t) {
            wf0[t] = fb[(t * 2 + 0) * 64 + lane];
            wf1[t] = fb[(t * 2 + 1) * 64 + lane];
        }
    }
    asm volatile("s_waitcnt vmcnt(0)" ::: "memory");
    __builtin_amdgcn_sched_barrier(0);

    // ---- PACK precompute: lane pair handles ring cell pcell, 16 channels --
    const int pcell = 32 * wv + (lane >> 1);         // swizzled cell id 0..159
    const int w1p   = w1s(pcell);                    // logical w (involution)
    const int wloc  = w1p - wv * 32;                 // 0..31 within wave panel
    const int chb   = (lane & 1) * 16;
    int soff[16];                                    // scratch byte offsets
    #pragma unroll
    for (int c = 0; c < 16; ++c) {
        const int ch = chb + c;
        soff[c] = (wv * 4 + (ch >> 3)) * 1024 + ((ch & 7) * 8 + (wloc >> 2)) * 16
                + (wloc & 3) * 4;
    }
    const int f2p = f2v(pcell);
    const int rb0 = pcell * 64 + ((((lane & 1) * 2)     ^ f2p) * 16);
    const int rb1 = pcell * 64 + ((((lane & 1) * 2 + 1) ^ f2p) * 16);

    // ---- COMPUTE precompute (R5 fragment path; w-edges via clamp+select) --
    const int s16 = lane & 15, kgr = lane >> 4;
    int rdo[2][3];
    #pragma unroll
    for (int gi = 0; gi < 2; ++gi)
        #pragma unroll
        for (int kw = 0; kw < 3; ++kw) {
            int wq = (2 * wv + gi) * 16 + s16 + kw - 1;      // -1..160
            wq = wq < 0 ? 0 : (wq > 159 ? 159 : wq);
            rdo[gi][kw] = (w1s(wq) * 32 + ((kgr ^ f2v(wq)) * 8)) * 2;  // bytes
        }
    const bool okA = (wv * 32 + s16 - 1) >= 0;        // site (gi=0,kw=0)
    const bool okB = (wv * 32 + 16 + s16 + 1) < 160;  // site (gi=1,kw=2)
    float* ob = out + (size_t)(n * 32 + s16) * DHW + d * HW + wv * 32 + kgr * 4;

    auto DMA = [&](int r) {            // 4 instrs/wave; clamped h (garbage OK)
        int h = h0 - 1 + r; h = h < 0 ? 0 : (h > 159 ? 159 : h);
        char* dst = lds + RING_B + wv * 4096;          // single scratch slot
        #pragma unroll
        for (int q = 0; q < 4; ++q)
            gld16(qb[q] + h * 160, dst + q * 1024);
        __builtin_amdgcn_sched_barrier(0);   // pin issue
    };
    auto PACK = [&](int r) {           // scratch f32 -> f16 ring (own-wave)
        const int hr = h0 - 1 + r;
        const char* sl = lds + RING_B;
        char* rg = lds + (r & 3) * RING_SLOT_B;
        half8 o0 = {}, o1 = {};
        if (hr >= 0 && hr < 160) {     // block-uniform; OOB rows -> zeros
            float f[16];
            #pragma unroll
            for (int c = 0; c < 16; ++c) f[c] = *(const float*)(sl + soff[c]);
            #pragma unroll
            for (int c = 0; c < 8; ++c) { o0[c] = (_Float16)f[c]; o1[c] = (_Float16)f[c + 8]; }
        }
        *(half8*)(rg + rb0) = o0;
        *(half8*)(rg + rb1) = o1;
    };
    auto COMPUTE = [&](int t) {        // output row h0+t; ring rows t..t+2
        const half8 zh = {};
        #pragma unroll
        for (int gi = 0; gi < 2; ++gi) {
            floatx4 a0 = {0.f, 0.f, 0.f, 0.f};
            floatx4 a1 = {0.f, 0.f, 0.f, 0.f};
            #pragma unroll
            for (int kh = 0; kh < 3; ++kh) {
                const char* sb = lds + ((t + kh) & 3) * RING_SLOT_B;
                #pragma unroll
                for (int kw = 0; kw < 3; ++kw) {
                    half8 a = *(const half8*)(sb + rdo[gi][kw]);
                    if (gi == 0 && kw == 0) a = okA ? a : zh;   // w = -1 edge
                    if (gi == 1 && kw == 2) a = okB ? a : zh;   // w = 160 edge
                    const int tp = kh * 3 + kw;
                    a0 = __builtin_amdgcn_mfma_f32_16x16x32_f16(a, wf0[tp], a0, 0, 0, 0);
                    a1 = __builtin_amdgcn_mfma_f32_16x16x32_f16(a, wf1[tp], a1, 0, 0, 0);
                }
            }
            float* op = ob + (size_t)(h0 + t) * 160 + gi * 16;
            *(floatx4*)op = a0;                       // o 0..15
            *(floatx4*)(op + (size_t)16 * DHW) = a1;  // o 16..31
        }
    };

    // ------------- pipeline (per-wave vmcnt audit: 4 DMA + 4 stores/unit) --
    // prologue: pack ring rows 0,1,2 (depth-1 scratch: wait-all each time)
    DMA(0);
    VMCNT(0); PACK(0); barrier_raw(); DMA(1);
    VMCNT(0); PACK(1); barrier_raw(); DMA(2);
    // t=0: outstanding {D2} -> wait-all; then D3 issued, S0 stores follow
    VMCNT(0); PACK(2); barrier_raw(); DMA(3); COMPUTE(0);
    // steady t=1..38: need D(t+2) done; younger = S(t-1) (4 stores)
    for (int t = 1; t <= 38; ++t) {
        VMCNT(4); PACK(t + 2); barrier_raw(); DMA(t + 3); COMPUTE(t);
    }
    // t=39: need D41 (issued t=38); younger = S38
    VMCNT(4); PACK(41); barrier_raw(); COMPUTE(39);
}

extern "C" void kernel_launch(void* const* d_in, const int* in_sizes, int n_in,
                              void* d_out, int out_size, void* d_ws, size_t ws_size,
                              hipStream_t stream) {
    const float* x = (const float*)d_in[0];
    const float* w = (const float*)d_in[1];
    float* out = (float*)d_out;
    _Float16* ws = (_Float16*)d_ws;     // 9216 halfs = 18 KB scratch
    bnn_wprep_kernel<<<dim3(1), dim3(256), 0, stream>>>(w, ws);
    // grid: 8 n * 16 d * 4 h-chunks of 40 rows -> 512 blocks, 2/CU resident
    bnn_conv3d_dma<<<dim3(512), dim3(320), 0, stream>>>(x, ws, out);
}